// Round 18
// baseline (88.945 us; speedup 1.0000x reference)
//
#include <hip/hip_runtime.h>

// GCNConv: out = D^-1/2 (A+I, dedup'd) D^-1/2 (X @ W)
// N=10000, IN_CH=256, OUT=256, E=320000
// R17: zero-global-atomic build WITHOUT scan replication (R13-15's flaw) and
//      WITHOUT shared counters (R10's flaw). Pass1: per-block partition of its
//      256 edges into 313 row-buckets (LDS hist positions, private global
//      regions, packed (r<<16)|c). Pass2: 313 merge blocks drain one bucket
//      column each into LDS lists + in-block wave dedup -> col_ell/cnt/dinv.
//      prep -> pass1||gemm -> merge -> gather. Gather/gemm unchanged from R12.

#define CH 256
#define ELLW 96   // max raw row count; Poisson(32) => P(>=96) ~ 1e-19 per row
#define CAP 12    // slots per (block,bucket); Poisson(0.82), P(>12) ~ 5e-12
#define RPBK 32   // rows per bucket
#define NBMAX 320 // static LDS hist size (>= (n+31)/32 = 313)

typedef __attribute__((ext_vector_type(8))) short short8;
typedef __attribute__((ext_vector_type(4))) float f32x4;

__device__ inline unsigned short f2b(float f) {   // fp32 -> bf16 RN-even
    unsigned x = __builtin_bit_cast(unsigned, f);
    x = (x + 0x7fffu + ((x >> 16) & 1u)) >> 16;
    return (unsigned short)x;
}
__device__ inline float b2f(unsigned short u) {
    unsigned v = ((unsigned)u) << 16;
    return __builtin_bit_cast(float, v);
}

// K1: W^T -> bf16 (cnt needs no clear: merge blocks are sole writers).
__global__ void prep_kernel(const float* __restrict__ w,
                            unsigned short* __restrict__ wt) {
    int idx = blockIdx.x * blockDim.x + threadIdx.x;   // = k*CH + nn
    if (idx < CH * CH) {
        int k = idx >> 8, nn = idx & 255;
        wt[nn * CH + k] = f2b(w[idx]);
    }
}

// K2: blocks [0,fillb): partition 256 own edges into buckets k=r>>5 via LDS
//     hist (no global atomics; private region per (block,bucket)).
//     blocks [fillb,..): MFMA GEMM, Z = X@W unscaled bf16, [2][n][128].
__global__ __launch_bounds__(256) void partgemm_kernel(
    const int* __restrict__ ei, int e_cnt, int nb,
    unsigned* __restrict__ region, int* __restrict__ counts,
    const float* __restrict__ x, const unsigned short* __restrict__ wt,
    unsigned short* __restrict__ zb, int n, int fillb) {
    __shared__ int hist[NBMAX];
    if ((int)blockIdx.x < fillb) {
        const int b = blockIdx.x;
        for (int i = threadIdx.x; i < nb; i += 256) hist[i] = 0;
        __syncthreads();
        int e = b * 256 + threadIdx.x;
        if (e < e_cnt) {
            int r = ei[e];
            int c = ei[e_cnt + e];
            int k = r >> 5;
            int p = atomicAdd(&hist[k], 1);           // LDS: cheap, contention ~1
            if (p < CAP)
                region[((size_t)b * nb + k) * CAP + p] = ((unsigned)r << 16) | (unsigned)c;
        }
        __syncthreads();
        for (int i = threadIdx.x; i < nb; i += 256) counts[(size_t)b * nb + i] = hist[i];
        return;
    }
    const int blk = blockIdx.x - fillb;
    const int tid = threadIdx.x;
    const int lane = tid & 63;
    const int wv = tid >> 6;
    const int m0 = blk * 16;
    const int n0 = wv * 64;
    const int rsel = lane & 15;
    const int kbase = (lane >> 4) * 8;

    const float* xrow = x + (size_t)(m0 + rsel) * CH + kbase;
    const unsigned short* b0p = wt + (size_t)(n0 + rsel) * CH + kbase;
    const unsigned short* b1p = b0p + 16 * CH;
    const unsigned short* b2p = b0p + 32 * CH;
    const unsigned short* b3p = b0p + 48 * CH;

    f32x4 acc0 = {0.f, 0.f, 0.f, 0.f};
    f32x4 acc1 = acc0, acc2 = acc0, acc3 = acc0;

#pragma unroll
    for (int kc = 0; kc < 8; ++kc) {
        const float4* p = (const float4*)(xrow + kc * 32);
        float4 u = p[0], v = p[1];
        short8 a;
        a[0] = (short)f2b(u.x); a[1] = (short)f2b(u.y);
        a[2] = (short)f2b(u.z); a[3] = (short)f2b(u.w);
        a[4] = (short)f2b(v.x); a[5] = (short)f2b(v.y);
        a[6] = (short)f2b(v.z); a[7] = (short)f2b(v.w);
        short8 b0 = *(const short8*)(b0p + kc * 32);
        short8 b1 = *(const short8*)(b1p + kc * 32);
        short8 b2 = *(const short8*)(b2p + kc * 32);
        short8 b3 = *(const short8*)(b3p + kc * 32);
        acc0 = __builtin_amdgcn_mfma_f32_16x16x32_bf16(a, b0, acc0, 0, 0, 0);
        acc1 = __builtin_amdgcn_mfma_f32_16x16x32_bf16(a, b1, acc1, 0, 0, 0);
        acc2 = __builtin_amdgcn_mfma_f32_16x16x32_bf16(a, b2, acc2, 0, 0, 0);
        acc3 = __builtin_amdgcn_mfma_f32_16x16x32_bf16(a, b3, acc3, 0, 0, 0);
    }

    const int r0 = (lane >> 4) * 4;
    const int slice = n0 >> 7;     // waves 0,1 -> slice 0; 2,3 -> slice 1
    const int nn0 = n0 & 127;
#pragma unroll
    for (int j = 0; j < 4; ++j) {
        unsigned short* zr = zb + ((size_t)slice * n + (m0 + r0 + j)) * 128 + nn0 + rsel;
        zr[0]  = f2b(acc0[j]);
        zr[16] = f2b(acc1[j]);
        zr[32] = f2b(acc2[j]);
        zr[48] = f2b(acc3[j]);
    }
}

// K3: merge. Block k drains bucket k across all fillb regions into LDS row
//     lists (rows [k*32,(k+1)*32)), then wave-dedups in-block and writes
//     col_ell / cnt / dinv. No global atomics; sole writer of its rows.
__global__ __launch_bounds__(256) void merge_kernel(
    const unsigned* __restrict__ region, const int* __restrict__ counts,
    int nb, int fillb, int* __restrict__ cnt, int* __restrict__ col_ell,
    float* __restrict__ dinv, int n) {
    __shared__ int lcol[RPBK][ELLW];   // 12 KB
    __shared__ int lcnt[RPBK];
    const int k = blockIdx.x;
    for (int i = threadIdx.x; i < RPBK; i += 256) lcnt[i] = 0;
    __syncthreads();

    for (int b = threadIdx.x; b < fillb; b += 256) {   // <=5 regions per thread
        int m = counts[(size_t)b * nb + k];
        if (m > CAP) m = CAP;
        const unsigned* rp = region + ((size_t)b * nb + k) * CAP;
        for (int j = 0; j < m; ++j) {
            unsigned u = rp[j];
            int ri = (int)(u >> 16) & (RPBK - 1);
            int c = (int)(u & 0xFFFFu);
            int p = atomicAdd(&lcnt[ri], 1);           // LDS atomic
            if (p < ELLW) lcol[ri][p] = c;
        }
    }
    __syncthreads();

    // wave-dedup epilogue (proven dedup logic on LDS lists)
    const int wv = threadIdx.x >> 6, lane = threadIdx.x & 63;
    const unsigned long long lt = (1ull << lane) - 1ull;
    for (int ri = wv; ri < RPBK; ri += 4) {
        const int r = k * RPBK + ri;
        if (r >= n) break;                             // wave-uniform
        int m = lcnt[ri]; if (m > ELLW) m = ELLW;
        const int e0 = lane, e1 = 64 + lane;
        int c0 = (e0 < m) ? lcol[ri][e0] : -1;
        int c1 = (e1 < m) ? lcol[ri][e1] : -1;
        bool dup0 = (c0 == r), dup1 = (c1 == r);
        for (int j = 0; j < m; ++j) {
            int cj = lcol[ri][j];                      // uniform -> LDS broadcast
            dup0 |= (j < e0) && (cj == c0);
            dup1 |= (j < e1) && (cj == c1);
        }
        unsigned long long b0 = __ballot((e0 < m) && !dup0);
        unsigned long long b1 = __ballot((e1 < m) && !dup1);
        int n0 = __popcll(b0);
        int mm = n0 + __popcll(b1);
        if ((e0 < m) && !dup0)
            col_ell[(size_t)r * ELLW + __popcll(b0 & lt)] = c0;
        if ((e1 < m) && !dup1)
            col_ell[(size_t)r * ELLW + n0 + __popcll(b1 & lt)] = c1;
        if (lane == 0) {
            cnt[r] = mm;
            dinv[r] = rsqrtf((float)(mm + 1));
        }
    }
}

// K4: gather. Block b: slice = b&1, rows (b>>1)*4 + wave. Lane group g=lane>>4
// handles neighbor slots g, g+4,...; acc += dinv[c]*Y[c]; out = dinv[r]*acc.
__global__ __launch_bounds__(256) void gather_kernel(
    const int* __restrict__ cnt, const int* __restrict__ col_ell,
    const float* __restrict__ dinv,
    const unsigned short* __restrict__ zb, float* __restrict__ out, int n) {
    const int b = blockIdx.x;
    const int slice = b & 1;
    const int wv = threadIdx.x >> 6;
    const int wid = (b >> 1) * 4 + wv;
    if (wid >= n) return;
    const int lane = threadIdx.x & 63;
    const int g = lane >> 4;          // neighbor phase 0..3
    const int chb = (lane & 15) * 8;  // 8 channels within the 128-ch slice
    int m = cnt[wid]; if (m > ELLW) m = ELLW;
    const int* cl = col_ell + (size_t)wid * ELLW;
    const unsigned short* zs = zb + (size_t)slice * n * 128 + chb;
    const float dr = dinv[wid];

    float acc[8];
    if (g == 0) {  // self term: dinv[r] * Y[r]
        short8 s = *(const short8*)(zs + (size_t)wid * 128);
#pragma unroll
        for (int q = 0; q < 8; ++q) acc[q] = dr * b2f((unsigned short)s[q]);
    } else {
#pragma unroll
        for (int q = 0; q < 8; ++q) acc[q] = 0.f;
    }

    int idx = g;
    for (; idx + 12 < m; idx += 16) {  // 4 quad-loads in flight (16 slots)
        int c0 = cl[idx], c1 = cl[idx + 4], c2 = cl[idx + 8], c3 = cl[idx + 12];
        float d0 = dinv[c0], d1 = dinv[c1], d2 = dinv[c2], d3 = dinv[c3];
        short8 v0 = *(const short8*)(zs + (size_t)c0 * 128);
        short8 v1 = *(const short8*)(zs + (size_t)c1 * 128);
        short8 v2 = *(const short8*)(zs + (size_t)c2 * 128);
        short8 v3 = *(const short8*)(zs + (size_t)c3 * 128);
#pragma unroll
        for (int q = 0; q < 8; ++q)
            acc[q] += d0 * b2f((unsigned short)v0[q]) + d1 * b2f((unsigned short)v1[q])
                    + d2 * b2f((unsigned short)v2[q]) + d3 * b2f((unsigned short)v3[q]);
    }
    for (; idx < m; idx += 4) {        // <=3 iterations
        int c = cl[idx];
        float dc = dinv[c];
        short8 v = *(const short8*)(zs + (size_t)c * 128);
#pragma unroll
        for (int q = 0; q < 8; ++q) acc[q] += dc * b2f((unsigned short)v[q]);
    }

    // combine the 4 lane groups (lanes L, L^16, L^32, L^48 share channels)
#pragma unroll
    for (int q = 0; q < 8; ++q) acc[q] += __shfl_xor(acc[q], 16);
#pragma unroll
    for (int q = 0; q < 8; ++q) acc[q] += __shfl_xor(acc[q], 32);

    if (g == 0) {
        float* dst = out + (size_t)wid * CH + slice * 128 + chb;
        float4 o0, o1;
        o0.x = acc[0] * dr; o0.y = acc[1] * dr; o0.z = acc[2] * dr; o0.w = acc[3] * dr;
        o1.x = acc[4] * dr; o1.y = acc[5] * dr; o1.z = acc[6] * dr; o1.w = acc[7] * dr;
        *(float4*)dst = o0;
        *(float4*)(dst + 4) = o1;
    }
}

extern "C" void kernel_launch(void* const* d_in, const int* in_sizes, int n_in,
                              void* d_out, int out_size, void* d_ws, size_t ws_size,
                              hipStream_t stream) {
    const float* x = (const float*)d_in[0];
    const float* w = (const float*)d_in[1];
    const int* ei = (const int*)d_in[2];
    float* out = (float*)d_out;

    const int n = in_sizes[0] / CH;      // 10000
    const int e_cnt = in_sizes[2] / 2;   // 320000
    const int nb = (n + RPBK - 1) / RPBK;     // 313 buckets
    const int fillb = (e_cnt + 255) / 256;    // 1250 partition blocks

    // workspace layout (all 16B-aligned)
    char* ws = (char*)d_ws;
    size_t off = 0;
    unsigned short* zb = (unsigned short*)(ws + off); off += (size_t)n * CH * 2;  // 5.12 MB
    unsigned short* wt = (unsigned short*)(ws + off); off += (size_t)CH * CH * 2; // 128 KB
    int* cnt = (int*)(ws + off);      off += (size_t)n * 4;                       // 40 KB
    float* dinv = (float*)(ws + off); off += (size_t)n * 4;                       // 40 KB
    int* col_ell = (int*)(ws + off);  off += (size_t)n * ELLW * 4;                // 3.84 MB
    unsigned* region = (unsigned*)(ws + off); off += (size_t)fillb * nb * CAP * 4; // 18.8 MB
    int* counts = (int*)(ws + off);   off += (size_t)fillb * nb * 4;              // 1.57 MB

    // K1: W^T -> bf16
    prep_kernel<<<(CH * CH + 255) / 256, 256, 0, stream>>>(w, wt);

    // K2: partition (1250 blocks) || gemm (625 blocks) -- no global atomics
    partgemm_kernel<<<fillb + n / 16, 256, 0, stream>>>(ei, e_cnt, nb, region, counts,
                                                        x, wt, zb, n, fillb);

    // K3: merge + in-block dedup (313 blocks)
    merge_kernel<<<nb, 256, 0, stream>>>(region, counts, nb, fillb, cnt, col_ell, dinv, n);

    // K4: gather (2 slices x n rows, 4 rows/block)
    gather_kernel<<<2 * ((n + 3) / 4), 256, 0, stream>>>(cnt, col_ell, dinv, zb, out, n);
}

// Round 19
// 72.081 us; speedup vs baseline: 1.2340x; 1.2340x over previous
//
#include <hip/hip_runtime.h>

// GCNConv: out = D^-1/2 (A+I, dedup'd) D^-1/2 (X @ W)
// N=10000, IN_CH=256, OUT=256, E=320000
// R18 (final config = R12, best measured 72.2us): padded-cnt atomic ELL fill
//     fused with MFMA gemm; wave dedup; dual-slice quad-neighbor gather.
//     Build-redesign campaign closed 0-for-6: fill is pinned ~38us by 320K
//     scattered device-scope atomic RMWs (invariant across padding/classing/
//     nt-store/partition/scan); gather pinned ~22us by random 256B reads at
//     ~2.3 TB/s. Floor model ~72us == measured.

#define CH 256
#define ELLW 96   // max raw row count; Poisson(32) => P(>=96) ~ 1e-19 per row
#define CPAD 16   // ints per row counter (64B = 1 line)

typedef __attribute__((ext_vector_type(8))) short short8;
typedef __attribute__((ext_vector_type(4))) float f32x4;

__device__ inline unsigned short f2b(float f) {   // fp32 -> bf16 RN-even
    unsigned x = __builtin_bit_cast(unsigned, f);
    x = (x + 0x7fffu + ((x >> 16) & 1u)) >> 16;
    return (unsigned short)x;
}
__device__ inline float b2f(unsigned short u) {
    unsigned v = ((unsigned)u) << 16;
    return __builtin_bit_cast(float, v);
}

// K1: clear padded cnt (n*CPAD ints, uint4-wide) + W^T -> bf16.
__global__ void prep_kernel(int* cnt, int n, const float* __restrict__ w,
                            unsigned short* __restrict__ wt) {
    int t = blockIdx.x * blockDim.x + threadIdx.x;
    const int nclr = n * CPAD / 4;    // 40000 uint4 stores
    if (t < nclr) {
        uint4 z = {0u, 0u, 0u, 0u};
        ((uint4*)cnt)[t] = z;
    } else if (t < nclr + CH * CH) {
        int idx = t - nclr;           // idx = k*CH + nn : coalesced read of w
        int k = idx >> 8, nn = idx & 255;
        wt[nn * CH + k] = f2b(w[idx]);
    }
}

// K2: blocks [0,fillb): per-edge ELL fill (padded cnt atomics);
//     blocks [fillb,fillb+n/16): MFMA GEMM, Z = X@W unscaled bf16, [2][n][128].
__global__ __launch_bounds__(256) void fillgemm_kernel(
    const int* __restrict__ ei, int e_cnt, int* cnt, int* __restrict__ col_ell,
    const float* __restrict__ x, const unsigned short* __restrict__ wt,
    unsigned short* __restrict__ zb, int n, int fillb) {
    if ((int)blockIdx.x < fillb) {
        int e = blockIdx.x * blockDim.x + threadIdx.x;
        if (e < e_cnt) {
            int r = ei[e];
            int c = ei[e_cnt + e];
            int pos = atomicAdd(&cnt[r << 4], 1);   // one line per row
            if (pos < ELLW) col_ell[(size_t)r * ELLW + pos] = c;
        }
        return;
    }
    const int blk = blockIdx.x - fillb;
    const int tid = threadIdx.x;
    const int lane = tid & 63;
    const int wv = tid >> 6;
    const int m0 = blk * 16;
    const int n0 = wv * 64;
    const int rsel = lane & 15;
    const int kbase = (lane >> 4) * 8;

    const float* xrow = x + (size_t)(m0 + rsel) * CH + kbase;
    const unsigned short* b0p = wt + (size_t)(n0 + rsel) * CH + kbase;
    const unsigned short* b1p = b0p + 16 * CH;
    const unsigned short* b2p = b0p + 32 * CH;
    const unsigned short* b3p = b0p + 48 * CH;

    f32x4 acc0 = {0.f, 0.f, 0.f, 0.f};
    f32x4 acc1 = acc0, acc2 = acc0, acc3 = acc0;

#pragma unroll
    for (int kc = 0; kc < 8; ++kc) {
        const float4* p = (const float4*)(xrow + kc * 32);
        float4 u = p[0], v = p[1];
        short8 a;
        a[0] = (short)f2b(u.x); a[1] = (short)f2b(u.y);
        a[2] = (short)f2b(u.z); a[3] = (short)f2b(u.w);
        a[4] = (short)f2b(v.x); a[5] = (short)f2b(v.y);
        a[6] = (short)f2b(v.z); a[7] = (short)f2b(v.w);
        short8 b0 = *(const short8*)(b0p + kc * 32);
        short8 b1 = *(const short8*)(b1p + kc * 32);
        short8 b2 = *(const short8*)(b2p + kc * 32);
        short8 b3 = *(const short8*)(b3p + kc * 32);
        acc0 = __builtin_amdgcn_mfma_f32_16x16x32_bf16(a, b0, acc0, 0, 0, 0);
        acc1 = __builtin_amdgcn_mfma_f32_16x16x32_bf16(a, b1, acc1, 0, 0, 0);
        acc2 = __builtin_amdgcn_mfma_f32_16x16x32_bf16(a, b2, acc2, 0, 0, 0);
        acc3 = __builtin_amdgcn_mfma_f32_16x16x32_bf16(a, b3, acc3, 0, 0, 0);
    }

    const int r0 = (lane >> 4) * 4;
    const int slice = n0 >> 7;     // waves 0,1 -> slice 0; 2,3 -> slice 1
    const int nn0 = n0 & 127;
#pragma unroll
    for (int j = 0; j < 4; ++j) {
        unsigned short* zr = zb + ((size_t)slice * n + (m0 + r0 + j)) * 128 + nn0 + rsel;
        zr[0]  = f2b(acc0[j]);
        zr[16] = f2b(acc1[j]);
        zr[32] = f2b(acc2[j]);
        zr[48] = f2b(acc3[j]);
    }
}

// K3: one wave per row: drop self-edges + duplicates, compact in place,
// write dinv[r] = rsqrt(m'+1). Rewrite col_ell only when something dropped.
__global__ __launch_bounds__(256) void dedup_kernel(
    int* cnt, int* __restrict__ col_ell, float* __restrict__ dinv, int n) {
    __shared__ int sh[4][ELLW];
    const int wv = threadIdx.x >> 6, lane = threadIdx.x & 63;
    const int r = blockIdx.x * 4 + wv;

    int m = 0;
    if (r < n) { m = cnt[r << 4]; if (m > ELLW) m = ELLW; }
    for (int e = lane; e < m; e += 64) sh[wv][e] = col_ell[(size_t)r * ELLW + e];
    __syncthreads();

    if (r < n) {
        const int e0 = lane, e1 = 64 + lane;
        int c0 = (e0 < m) ? sh[wv][e0] : -1;
        int c1 = (e1 < m) ? sh[wv][e1] : -1;
        bool dup0 = (c0 == r), dup1 = (c1 == r);
        for (int k = 0; k < m; ++k) {
            int ck = sh[wv][k];                 // uniform -> LDS broadcast
            dup0 |= (k < e0) && (ck == c0);
            dup1 |= (k < e1) && (ck == c1);
        }
        unsigned long long b0 = __ballot((e0 < m) && !dup0);
        unsigned long long b1 = __ballot((e1 < m) && !dup1);
        unsigned long long lt = (1ull << lane) - 1ull;
        int n0 = __popcll(b0);
        int mm = n0 + __popcll(b1);
        if (mm != m) {  // only rewrite rows that actually had drops
            if ((e0 < m) && !dup0)
                col_ell[(size_t)r * ELLW + __popcll(b0 & lt)] = c0;
            if ((e1 < m) && !dup1)
                col_ell[(size_t)r * ELLW + n0 + __popcll(b1 & lt)] = c1;
            if (lane == 0) cnt[r << 4] = mm;
        }
        if (lane == 0) dinv[r] = rsqrtf((float)(mm + 1));
    }
}

// K4: gather. Block b: slice = b&1, rows (b>>1)*4 + wave. Lane group g=lane>>4
// handles neighbor slots g, g+4,...; acc += dinv[c]*Y[c]; out = dinv[r]*acc.
__global__ __launch_bounds__(256) void gather_kernel(
    const int* __restrict__ cnt, const int* __restrict__ col_ell,
    const float* __restrict__ dinv,
    const unsigned short* __restrict__ zb, float* __restrict__ out, int n) {
    const int b = blockIdx.x;
    const int slice = b & 1;
    const int wv = threadIdx.x >> 6;
    const int wid = (b >> 1) * 4 + wv;
    if (wid >= n) return;
    const int lane = threadIdx.x & 63;
    const int g = lane >> 4;          // neighbor phase 0..3
    const int chb = (lane & 15) * 8;  // 8 channels within the 128-ch slice
    int m = cnt[wid << 4]; if (m > ELLW) m = ELLW;
    const int* cl = col_ell + (size_t)wid * ELLW;
    const unsigned short* zs = zb + (size_t)slice * n * 128 + chb;
    const float dr = dinv[wid];

    float acc[8];
    if (g == 0) {  // self term: dinv[r] * Y[r]
        short8 s = *(const short8*)(zs + (size_t)wid * 128);
#pragma unroll
        for (int q = 0; q < 8; ++q) acc[q] = dr * b2f((unsigned short)s[q]);
    } else {
#pragma unroll
        for (int q = 0; q < 8; ++q) acc[q] = 0.f;
    }

    int idx = g;
    for (; idx + 12 < m; idx += 16) {  // 4 quad-loads in flight (16 slots)
        int c0 = cl[idx], c1 = cl[idx + 4], c2 = cl[idx + 8], c3 = cl[idx + 12];
        float d0 = dinv[c0], d1 = dinv[c1], d2 = dinv[c2], d3 = dinv[c3];
        short8 v0 = *(const short8*)(zs + (size_t)c0 * 128);
        short8 v1 = *(const short8*)(zs + (size_t)c1 * 128);
        short8 v2 = *(const short8*)(zs + (size_t)c2 * 128);
        short8 v3 = *(const short8*)(zs + (size_t)c3 * 128);
#pragma unroll
        for (int q = 0; q < 8; ++q)
            acc[q] += d0 * b2f((unsigned short)v0[q]) + d1 * b2f((unsigned short)v1[q])
                    + d2 * b2f((unsigned short)v2[q]) + d3 * b2f((unsigned short)v3[q]);
    }
    for (; idx < m; idx += 4) {        // <=3 iterations
        int c = cl[idx];
        float dc = dinv[c];
        short8 v = *(const short8*)(zs + (size_t)c * 128);
#pragma unroll
        for (int q = 0; q < 8; ++q) acc[q] += dc * b2f((unsigned short)v[q]);
    }

    // combine the 4 lane groups (lanes L, L^16, L^32, L^48 share channels)
#pragma unroll
    for (int q = 0; q < 8; ++q) acc[q] += __shfl_xor(acc[q], 16);
#pragma unroll
    for (int q = 0; q < 8; ++q) acc[q] += __shfl_xor(acc[q], 32);

    if (g == 0) {
        float* dst = out + (size_t)wid * CH + slice * 128 + chb;
        float4 o0, o1;
        o0.x = acc[0] * dr; o0.y = acc[1] * dr; o0.z = acc[2] * dr; o0.w = acc[3] * dr;
        o1.x = acc[4] * dr; o1.y = acc[5] * dr; o1.z = acc[6] * dr; o1.w = acc[7] * dr;
        *(float4*)dst = o0;
        *(float4*)(dst + 4) = o1;
    }
}

extern "C" void kernel_launch(void* const* d_in, const int* in_sizes, int n_in,
                              void* d_out, int out_size, void* d_ws, size_t ws_size,
                              hipStream_t stream) {
    const float* x = (const float*)d_in[0];
    const float* w = (const float*)d_in[1];
    const int* ei = (const int*)d_in[2];
    float* out = (float*)d_out;

    const int n = in_sizes[0] / CH;      // 10000
    const int e_cnt = in_sizes[2] / 2;   // 320000

    // workspace layout (all 16B-aligned)
    char* ws = (char*)d_ws;
    size_t off = 0;
    unsigned short* zb = (unsigned short*)(ws + off); off += (size_t)n * CH * 2;  // 5.12 MB
    unsigned short* wt = (unsigned short*)(ws + off); off += (size_t)CH * CH * 2; // 128 KB
    int* cnt = (int*)(ws + off);      off += (size_t)n * CPAD * 4;                // 640 KB
    float* dinv = (float*)(ws + off); off += (size_t)n * 4;                       // 40 KB
    int* col_ell = (int*)(ws + off);  off += (size_t)n * ELLW * 4;                // 3.84 MB

    // K1: clear padded cnt + convert W^T
    const int prep_threads = n * CPAD / 4 + CH * CH;
    prep_kernel<<<(prep_threads + 255) / 256, 256, 0, stream>>>(cnt, n, w, wt);

    // K2: fill (1250 blocks) || gemm (625 blocks)
    const int fillb = (e_cnt + 255) / 256;
    fillgemm_kernel<<<fillb + n / 16, 256, 0, stream>>>(ei, e_cnt, cnt, col_ell,
                                                        x, wt, zb, n, fillb);

    // K3: dedup + dinv
    dedup_kernel<<<(n + 3) / 4, 256, 0, stream>>>(cnt, col_ell, dinv, n);

    // K4: gather (2 slices x n rows, 4 rows/block)
    gather_kernel<<<2 * ((n + 3) / 4), 256, 0, stream>>>(cnt, col_ell, dinv, zb, out, n);
}